// Round 25
// baseline (227.054 us; speedup 1.0000x reference)
//
#include <hip/hip_runtime.h>
#include <hip/hip_bf16.h>
#include <math.h>

// OptimizeSNR R25 = R22 (best: 70.2 us) with __launch_bounds__(256, 8):
// declare 8 waves/EU (32 waves/CU) to force max residency; VGPR 60 fits the
// <=64 budget. Single-change occupancy A/B on the best-known kernel.
constexpr int Bc = 8, Cc = 128, Lc = 32768, Kc = 129;

constexpr int MLEN = 256;              // outputs per tile
constexpr int T    = 16;               // tiles per wave
constexpr int NSEG = Lc / (MLEN * T);  // 8
constexpr int WPB  = 4;
constexpr int THREADS = 64 * WPB;      // 256
constexpr int LASTCW  = Lc / MLEN - 1; // 127

typedef __attribute__((ext_vector_type(8))) short short8;
typedef __attribute__((ext_vector_type(4))) float floatx4;

#define WAITVM(N) do { asm volatile("s_waitcnt vmcnt(" #N ")" ::: "memory"); \
                       __builtin_amdgcn_sched_barrier(0); } while (0)

__device__ __forceinline__ unsigned short f2bf(float f) {
    return __builtin_bit_cast(unsigned short, __float2bfloat16(f));
}

__device__ __forceinline__ short8 cvt8(const float4& a, const float4& b) {
    __hip_bfloat162 p0 = __float22bfloat162_rn(make_float2(a.x, a.y));
    __hip_bfloat162 p1 = __float22bfloat162_rn(make_float2(a.z, a.w));
    __hip_bfloat162 p2 = __float22bfloat162_rn(make_float2(b.x, b.y));
    __hip_bfloat162 p3 = __float22bfloat162_rn(make_float2(b.z, b.w));
    ushort2 u0, u1, u2, u3;
    __builtin_memcpy(&u0, &p0, 4);
    __builtin_memcpy(&u1, &p1, 4);
    __builtin_memcpy(&u2, &p2, 4);
    __builtin_memcpy(&u3, &p3, 4);
    short8 r;
    r[0] = (short)u0.x; r[1] = (short)u0.y;
    r[2] = (short)u1.x; r[3] = (short)u1.y;
    r[4] = (short)u2.x; r[5] = (short)u2.y;
    r[6] = (short)u3.x; r[7] = (short)u3.y;
    return r;
}

// Per-channel complex scale: sc = nm*cos(atan(a)), ss = nm*sin(atan(a))
__global__ void scale_kernel(const float* __restrict__ wm,
                             const float* __restrict__ wa,
                             float* __restrict__ ws, int C, float batchf) {
    int c = threadIdx.x;
    if (c >= C) return;
    float m = -1e30f;
    for (int i = 0; i < C; ++i) m = fmaxf(m, wm[i]);
    float s = 0.f;
    for (int i = 0; i < C; ++i) s += expf(wm[i] - m);
    float nm = batchf * expf(wm[c] - m) / s;
    float a = wa[c];
    float inv = rsqrtf(1.f + a * a);
    ws[2 * c]     = nm * inv;       // sc
    ws[2 * c + 1] = nm * a * inv;   // ss
}

__global__ __launch_bounds__(THREADS, 8)
void mf_kernel(const float* __restrict__ x,
               const float* __restrict__ kr,
               const float* __restrict__ ki,
               const float* __restrict__ sc_ss,
               float* __restrict__ out, int interleaved) {
    __shared__ __align__(16) unsigned short lb[WPB][512];   // 4 KB: bf16 windows

    const int seg = blockIdx.x;            // 8 segments
    const int rg  = blockIdx.y;            // 256 row groups (4 rows)
    const int tid = threadIdx.x;
    const int lane= tid & 63;
    const int wv  = tid >> 6;
    const int fh  = lane >> 4;             // 0..3
    const int fn  = lane & 15;             // 0..15

    const int row = rg * WPB + wv;         // 0..1023
    const int cw0 = seg * T;

    // ---- B fragments (k-Toeplitz): B_d[kl][n] = k[32d+kl-n]; lane: n=fn, kl=8*fh+e
    short8 br[5], bi[5];
    #pragma unroll
    for (int d = 0; d < 5; ++d) {
        #pragma unroll
        for (int e = 0; e < 8; ++e) {
            int idx = 32 * d + 8 * fh + e - fn;
            bool ok = (idx >= 0) && (idx < Kc);
            br[d][e] = (short)f2bf(ok ? kr[idx] : 0.f);
            bi[d][e] = (short)f2bf(ok ? ki[idx] : 0.f);
        }
    }

    const int ch = row & (Cc - 1);
    const float scv = sc_ss[2 * ch];
    const float ssv = sc_ss[2 * ch + 1];

    const float* __restrict__ xrow = x + (size_t)row * Lc;

    float4 F[2][2];
    auto ISSUE = [&](int cw, int buf0) {
        int g = cw * MLEN - 64 + 8 * lane;
        g = min(max(g, 0), Lc - 8);        // no-op interior, clamps edges
        F[buf0][0] = *reinterpret_cast<const float4*>(xrow + g);
        F[buf0][1] = *reinterpret_cast<const float4*>(xrow + g + 4);
    };

    // ---- prologue ----
    ISSUE(cw0, 0);
    ISSUE(cw0 + 1, 1);

    #pragma unroll
    for (int c = 0; c < T; ++c) {
        const int cw  = cw0 + c;
        const int buf = c & 1;

        // Drain ONLY tile-c's 2 loads; never wait on store acks.
        if (c == 0)          WAITVM(2);
        else if (c == 1)     WAITVM(6);
        else if (c == T - 1) WAITVM(8);
        else                 WAITVM(10);

        // window -> 8 bf16 (one 16B granule) per lane, single ds_write_b128
        short8 h = cvt8(F[buf][0], F[buf][1]);

        // F[buf] dead -> issue tile c+2's loads now
        if (c + 2 < T) ISSUE(cw + 2, buf);

        *reinterpret_cast<short8*>(&lb[wv][8 * lane]) = h;

        floatx4 cr = {0.f, 0.f, 0.f, 0.f};
        floatx4 ci = {0.f, 0.f, 0.f, 0.f};
        #pragma unroll
        for (int d = 0; d < 5; ++d) {
            // fragment = window shorts [16fn+8fh+32d, +8) = granule 2fn+fh+4d
            short8 a = *reinterpret_cast<const short8*>(
                &lb[wv][16 * fn + 8 * fh + 32 * d]);
            // edge zeroing: granule gg holds garbage iff clamped at load
            if (cw == 0) {
                if (2 * fn + fh + 4 * d < 8) a = short8{0,0,0,0,0,0,0,0};
            } else if (cw == LASTCW) {
                if (2 * fn + fh + 4 * d >= 40) a = short8{0,0,0,0,0,0,0,0};
            }
            cr = __builtin_amdgcn_mfma_f32_16x16x32_bf16(a, br[d], cr, 0, 0, 0);
            ci = __builtin_amdgcn_mfma_f32_16x16x32_bf16(a, bi[d], ci, 0, 0, 0);
        }

        // D[m=4*fh+r][n=fn]; output pos = cw*256 + 64*fh + 16*r + fn
        if (!interleaved) {
            float* op = out + (size_t)row * Lc + cw * MLEN + 64 * fh + fn;
            #pragma unroll
            for (int r = 0; r < 4; ++r)
                op[16 * r] = scv * cr[r] - ssv * ci[r];
        } else {
            float2* op = reinterpret_cast<float2*>(out) +
                         ((size_t)row * Lc + cw * MLEN + 64 * fh + fn);
            #pragma unroll
            for (int r = 0; r < 4; ++r)
                op[16 * r] = make_float2(scv * cr[r] - ssv * ci[r],
                                         -scv * ci[r] - ssv * cr[r]);
        }
    }
}

extern "C" void kernel_launch(void* const* d_in, const int* in_sizes, int n_in,
                              void* d_out, int out_size, void* d_ws, size_t ws_size,
                              hipStream_t stream) {
    const float* x  = (const float*)d_in[0];
    const float* wm = (const float*)d_in[1];
    const float* wa = (const float*)d_in[2];
    const float* kr = (const float*)d_in[3];
    const float* ki = (const float*)d_in[4];
    float* out = (float*)d_out;
    float* ws  = (float*)d_ws;

    const int C = in_sizes[1];  // 128
    const long long N = (long long)Bc * Cc * Lc;
    const int interleaved = (out_size == 2 * N) ? 1 : 0;

    hipLaunchKernelGGL(scale_kernel, dim3(1), dim3(C), 0, stream,
                       wm, wa, ws, C, (float)Bc);

    dim3 grid(NSEG, (Bc * Cc) / WPB);   // 8 x 256 = 2048 blocks
    hipLaunchKernelGGL(mf_kernel, grid, dim3(THREADS), 0, stream,
                       x, kr, ki, ws, out, interleaved);
}

// Round 26
// 212.182 us; speedup vs baseline: 1.0701x; 1.0701x over previous
//
#include <hip/hip_runtime.h>
#include <hip/hip_bf16.h>
#include <math.h>

// OptimizeSNR R26 = R22 with a register diet (single prefetch buffer: F[2]
// instead of F[2][2], saves 8 VGPRs -> est. 60 unified regs <= 64) and
// __launch_bounds__(256, 8) for 8 waves/SIMD residency.
// Trade: prefetch depth 1 (less ILP cover) for 2x TLP (more waves).
constexpr int Bc = 8, Cc = 128, Lc = 32768, Kc = 129;

constexpr int MLEN = 256;              // outputs per tile
constexpr int T    = 16;               // tiles per wave
constexpr int NSEG = Lc / (MLEN * T);  // 8
constexpr int WPB  = 4;
constexpr int THREADS = 64 * WPB;      // 256
constexpr int LASTCW  = Lc / MLEN - 1; // 127

typedef __attribute__((ext_vector_type(8))) short short8;
typedef __attribute__((ext_vector_type(4))) float floatx4;

#define WAITVM(N) do { asm volatile("s_waitcnt vmcnt(" #N ")" ::: "memory"); \
                       __builtin_amdgcn_sched_barrier(0); } while (0)

__device__ __forceinline__ unsigned short f2bf(float f) {
    return __builtin_bit_cast(unsigned short, __float2bfloat16(f));
}

__device__ __forceinline__ short8 cvt8(const float4& a, const float4& b) {
    __hip_bfloat162 p0 = __float22bfloat162_rn(make_float2(a.x, a.y));
    __hip_bfloat162 p1 = __float22bfloat162_rn(make_float2(a.z, a.w));
    __hip_bfloat162 p2 = __float22bfloat162_rn(make_float2(b.x, b.y));
    __hip_bfloat162 p3 = __float22bfloat162_rn(make_float2(b.z, b.w));
    ushort2 u0, u1, u2, u3;
    __builtin_memcpy(&u0, &p0, 4);
    __builtin_memcpy(&u1, &p1, 4);
    __builtin_memcpy(&u2, &p2, 4);
    __builtin_memcpy(&u3, &p3, 4);
    short8 r;
    r[0] = (short)u0.x; r[1] = (short)u0.y;
    r[2] = (short)u1.x; r[3] = (short)u1.y;
    r[4] = (short)u2.x; r[5] = (short)u2.y;
    r[6] = (short)u3.x; r[7] = (short)u3.y;
    return r;
}

// Per-channel complex scale: sc = nm*cos(atan(a)), ss = nm*sin(atan(a))
__global__ void scale_kernel(const float* __restrict__ wm,
                             const float* __restrict__ wa,
                             float* __restrict__ ws, int C, float batchf) {
    int c = threadIdx.x;
    if (c >= C) return;
    float m = -1e30f;
    for (int i = 0; i < C; ++i) m = fmaxf(m, wm[i]);
    float s = 0.f;
    for (int i = 0; i < C; ++i) s += expf(wm[i] - m);
    float nm = batchf * expf(wm[c] - m) / s;
    float a = wa[c];
    float inv = rsqrtf(1.f + a * a);
    ws[2 * c]     = nm * inv;       // sc
    ws[2 * c + 1] = nm * a * inv;   // ss
}

__global__ __launch_bounds__(THREADS, 8)
void mf_kernel(const float* __restrict__ x,
               const float* __restrict__ kr,
               const float* __restrict__ ki,
               const float* __restrict__ sc_ss,
               float* __restrict__ out, int interleaved) {
    __shared__ __align__(16) unsigned short lb[WPB][512];   // 4 KB: bf16 windows

    const int seg = blockIdx.x;            // 8 segments
    const int rg  = blockIdx.y;            // 256 row groups (4 rows)
    const int tid = threadIdx.x;
    const int lane= tid & 63;
    const int wv  = tid >> 6;
    const int fh  = lane >> 4;             // 0..3
    const int fn  = lane & 15;             // 0..15

    const int row = rg * WPB + wv;         // 0..1023
    const int cw0 = seg * T;

    // ---- B fragments (k-Toeplitz): B_d[kl][n] = k[32d+kl-n]; lane: n=fn, kl=8*fh+e
    short8 br[5], bi[5];
    #pragma unroll
    for (int d = 0; d < 5; ++d) {
        #pragma unroll
        for (int e = 0; e < 8; ++e) {
            int idx = 32 * d + 8 * fh + e - fn;
            bool ok = (idx >= 0) && (idx < Kc);
            br[d][e] = (short)f2bf(ok ? kr[idx] : 0.f);
            bi[d][e] = (short)f2bf(ok ? ki[idx] : 0.f);
        }
    }

    const int ch = row & (Cc - 1);
    const float scv = sc_ss[2 * ch];
    const float ssv = sc_ss[2 * ch + 1];

    const float* __restrict__ xrow = x + (size_t)row * Lc;

    float4 F[2];                           // single prefetch buffer (8 VGPRs)
    auto ISSUE = [&](int cw) {
        int g = cw * MLEN - 64 + 8 * lane;
        g = min(max(g, 0), Lc - 8);        // no-op interior, clamps edges
        F[0] = *reinterpret_cast<const float4*>(xrow + g);
        F[1] = *reinterpret_cast<const float4*>(xrow + g + 4);
    };

    // ---- prologue ----
    ISSUE(cw0);

    #pragma unroll
    for (int c = 0; c < T; ++c) {
        const int cw = cw0 + c;

        // Drain ONLY tile-c's 2 loads (oldest); leave c-1's 4 stores in flight.
        if (c == 0) WAITVM(0);
        else        WAITVM(4);

        // window -> 8 bf16 (one 16B granule) per lane
        short8 h = cvt8(F[0], F[1]);

        // F dead -> issue tile c+1's loads now (depth-1 prefetch)
        if (c + 1 < T) ISSUE(cw + 1);

        *reinterpret_cast<short8*>(&lb[wv][8 * lane]) = h;

        floatx4 cr = {0.f, 0.f, 0.f, 0.f};
        floatx4 ci = {0.f, 0.f, 0.f, 0.f};
        #pragma unroll
        for (int d = 0; d < 5; ++d) {
            // fragment = window shorts [16fn+8fh+32d, +8) = granule 2fn+fh+4d
            short8 a = *reinterpret_cast<const short8*>(
                &lb[wv][16 * fn + 8 * fh + 32 * d]);
            // edge zeroing: granule gg holds garbage iff clamped at load
            if (cw == 0) {
                if (2 * fn + fh + 4 * d < 8) a = short8{0,0,0,0,0,0,0,0};
            } else if (cw == LASTCW) {
                if (2 * fn + fh + 4 * d >= 40) a = short8{0,0,0,0,0,0,0,0};
            }
            cr = __builtin_amdgcn_mfma_f32_16x16x32_bf16(a, br[d], cr, 0, 0, 0);
            ci = __builtin_amdgcn_mfma_f32_16x16x32_bf16(a, bi[d], ci, 0, 0, 0);
        }

        // D[m=4*fh+r][n=fn]; output pos = cw*256 + 64*fh + 16*r + fn
        if (!interleaved) {
            float* op = out + (size_t)row * Lc + cw * MLEN + 64 * fh + fn;
            #pragma unroll
            for (int r = 0; r < 4; ++r)
                op[16 * r] = scv * cr[r] - ssv * ci[r];
        } else {
            float2* op = reinterpret_cast<float2*>(out) +
                         ((size_t)row * Lc + cw * MLEN + 64 * fh + fn);
            #pragma unroll
            for (int r = 0; r < 4; ++r)
                op[16 * r] = make_float2(scv * cr[r] - ssv * ci[r],
                                         -scv * ci[r] - ssv * cr[r]);
        }
    }
}

extern "C" void kernel_launch(void* const* d_in, const int* in_sizes, int n_in,
                              void* d_out, int out_size, void* d_ws, size_t ws_size,
                              hipStream_t stream) {
    const float* x  = (const float*)d_in[0];
    const float* wm = (const float*)d_in[1];
    const float* wa = (const float*)d_in[2];
    const float* kr = (const float*)d_in[3];
    const float* ki = (const float*)d_in[4];
    float* out = (float*)d_out;
    float* ws  = (float*)d_ws;

    const int C = in_sizes[1];  // 128
    const long long N = (long long)Bc * Cc * Lc;
    const int interleaved = (out_size == 2 * N) ? 1 : 0;

    hipLaunchKernelGGL(scale_kernel, dim3(1), dim3(C), 0, stream,
                       wm, wa, ws, C, (float)Bc);

    dim3 grid(NSEG, (Bc * Cc) / WPB);   // 8 x 256 = 2048 blocks
    hipLaunchKernelGGL(mf_kernel, grid, dim3(THREADS), 0, stream,
                       x, kr, ki, ws, out, interleaved);
}

// Round 27
// 70.558 us; speedup vs baseline: 3.2180x; 3.0072x over previous
//
#include <hip/hip_runtime.h>
#include <hip/hip_bf16.h>
#include <math.h>

// OptimizeSNR R27 = R22 with 8-wave workgroups (512 thr): same per-wave
// program, same counted vmcnt, zero barriers; tests whether resident-block
// count (not regs/LDS) limits occupancy. Grid 8 x 128 = 1024 blocks.
constexpr int Bc = 8, Cc = 128, Lc = 32768, Kc = 129;

constexpr int MLEN = 256;              // outputs per tile
constexpr int T    = 16;               // tiles per wave
constexpr int NSEG = Lc / (MLEN * T);  // 8
constexpr int WPB  = 8;                // waves per block (was 4)
constexpr int THREADS = 64 * WPB;      // 512
constexpr int LASTCW  = Lc / MLEN - 1; // 127

typedef __attribute__((ext_vector_type(8))) short short8;
typedef __attribute__((ext_vector_type(4))) float floatx4;

#define WAITVM(N) do { asm volatile("s_waitcnt vmcnt(" #N ")" ::: "memory"); \
                       __builtin_amdgcn_sched_barrier(0); } while (0)

__device__ __forceinline__ unsigned short f2bf(float f) {
    return __builtin_bit_cast(unsigned short, __float2bfloat16(f));
}

__device__ __forceinline__ short8 cvt8(const float4& a, const float4& b) {
    __hip_bfloat162 p0 = __float22bfloat162_rn(make_float2(a.x, a.y));
    __hip_bfloat162 p1 = __float22bfloat162_rn(make_float2(a.z, a.w));
    __hip_bfloat162 p2 = __float22bfloat162_rn(make_float2(b.x, b.y));
    __hip_bfloat162 p3 = __float22bfloat162_rn(make_float2(b.z, b.w));
    ushort2 u0, u1, u2, u3;
    __builtin_memcpy(&u0, &p0, 4);
    __builtin_memcpy(&u1, &p1, 4);
    __builtin_memcpy(&u2, &p2, 4);
    __builtin_memcpy(&u3, &p3, 4);
    short8 r;
    r[0] = (short)u0.x; r[1] = (short)u0.y;
    r[2] = (short)u1.x; r[3] = (short)u1.y;
    r[4] = (short)u2.x; r[5] = (short)u2.y;
    r[6] = (short)u3.x; r[7] = (short)u3.y;
    return r;
}

// Per-channel complex scale: sc = nm*cos(atan(a)), ss = nm*sin(atan(a))
__global__ void scale_kernel(const float* __restrict__ wm,
                             const float* __restrict__ wa,
                             float* __restrict__ ws, int C, float batchf) {
    int c = threadIdx.x;
    if (c >= C) return;
    float m = -1e30f;
    for (int i = 0; i < C; ++i) m = fmaxf(m, wm[i]);
    float s = 0.f;
    for (int i = 0; i < C; ++i) s += expf(wm[i] - m);
    float nm = batchf * expf(wm[c] - m) / s;
    float a = wa[c];
    float inv = rsqrtf(1.f + a * a);
    ws[2 * c]     = nm * inv;       // sc
    ws[2 * c + 1] = nm * a * inv;   // ss
}

__global__ __launch_bounds__(THREADS, 4)
void mf_kernel(const float* __restrict__ x,
               const float* __restrict__ kr,
               const float* __restrict__ ki,
               const float* __restrict__ sc_ss,
               float* __restrict__ out, int interleaved) {
    __shared__ __align__(16) unsigned short lb[WPB][512];   // 8 KB: bf16 windows

    const int seg = blockIdx.x;            // 8 segments
    const int rg  = blockIdx.y;            // 128 row groups (8 rows)
    const int tid = threadIdx.x;
    const int lane= tid & 63;
    const int wv  = tid >> 6;              // 0..7
    const int fh  = lane >> 4;             // 0..3
    const int fn  = lane & 15;             // 0..15

    const int row = rg * WPB + wv;         // 0..1023
    const int cw0 = seg * T;

    // ---- B fragments (k-Toeplitz): B_d[kl][n] = k[32d+kl-n]; lane: n=fn, kl=8*fh+e
    short8 br[5], bi[5];
    #pragma unroll
    for (int d = 0; d < 5; ++d) {
        #pragma unroll
        for (int e = 0; e < 8; ++e) {
            int idx = 32 * d + 8 * fh + e - fn;
            bool ok = (idx >= 0) && (idx < Kc);
            br[d][e] = (short)f2bf(ok ? kr[idx] : 0.f);
            bi[d][e] = (short)f2bf(ok ? ki[idx] : 0.f);
        }
    }

    const int ch = row & (Cc - 1);
    const float scv = sc_ss[2 * ch];
    const float ssv = sc_ss[2 * ch + 1];

    const float* __restrict__ xrow = x + (size_t)row * Lc;

    float4 F[2][2];
    auto ISSUE = [&](int cw, int buf0) {
        int g = cw * MLEN - 64 + 8 * lane;
        g = min(max(g, 0), Lc - 8);        // no-op interior, clamps edges
        F[buf0][0] = *reinterpret_cast<const float4*>(xrow + g);
        F[buf0][1] = *reinterpret_cast<const float4*>(xrow + g + 4);
    };

    // ---- prologue ----
    ISSUE(cw0, 0);
    ISSUE(cw0 + 1, 1);

    #pragma unroll
    for (int c = 0; c < T; ++c) {
        const int cw  = cw0 + c;
        const int buf = c & 1;

        // Drain ONLY tile-c's 2 loads; never wait on store acks.
        if (c == 0)          WAITVM(2);
        else if (c == 1)     WAITVM(6);
        else if (c == T - 1) WAITVM(8);
        else                 WAITVM(10);

        // window -> 8 bf16 (one 16B granule) per lane, single ds_write_b128
        short8 h = cvt8(F[buf][0], F[buf][1]);

        // F[buf] dead -> issue tile c+2's loads now
        if (c + 2 < T) ISSUE(cw + 2, buf);

        *reinterpret_cast<short8*>(&lb[wv][8 * lane]) = h;

        floatx4 cr = {0.f, 0.f, 0.f, 0.f};
        floatx4 ci = {0.f, 0.f, 0.f, 0.f};
        #pragma unroll
        for (int d = 0; d < 5; ++d) {
            // fragment = window shorts [16fn+8fh+32d, +8) = granule 2fn+fh+4d
            short8 a = *reinterpret_cast<const short8*>(
                &lb[wv][16 * fn + 8 * fh + 32 * d]);
            // edge zeroing: granule gg holds garbage iff clamped at load
            if (cw == 0) {
                if (2 * fn + fh + 4 * d < 8) a = short8{0,0,0,0,0,0,0,0};
            } else if (cw == LASTCW) {
                if (2 * fn + fh + 4 * d >= 40) a = short8{0,0,0,0,0,0,0,0};
            }
            cr = __builtin_amdgcn_mfma_f32_16x16x32_bf16(a, br[d], cr, 0, 0, 0);
            ci = __builtin_amdgcn_mfma_f32_16x16x32_bf16(a, bi[d], ci, 0, 0, 0);
        }

        // D[m=4*fh+r][n=fn]; output pos = cw*256 + 64*fh + 16*r + fn
        if (!interleaved) {
            float* op = out + (size_t)row * Lc + cw * MLEN + 64 * fh + fn;
            #pragma unroll
            for (int r = 0; r < 4; ++r)
                op[16 * r] = scv * cr[r] - ssv * ci[r];
        } else {
            float2* op = reinterpret_cast<float2*>(out) +
                         ((size_t)row * Lc + cw * MLEN + 64 * fh + fn);
            #pragma unroll
            for (int r = 0; r < 4; ++r)
                op[16 * r] = make_float2(scv * cr[r] - ssv * ci[r],
                                         -scv * ci[r] - ssv * cr[r]);
        }
    }
}

extern "C" void kernel_launch(void* const* d_in, const int* in_sizes, int n_in,
                              void* d_out, int out_size, void* d_ws, size_t ws_size,
                              hipStream_t stream) {
    const float* x  = (const float*)d_in[0];
    const float* wm = (const float*)d_in[1];
    const float* wa = (const float*)d_in[2];
    const float* kr = (const float*)d_in[3];
    const float* ki = (const float*)d_in[4];
    float* out = (float*)d_out;
    float* ws  = (float*)d_ws;

    const int C = in_sizes[1];  // 128
    const long long N = (long long)Bc * Cc * Lc;
    const int interleaved = (out_size == 2 * N) ? 1 : 0;

    hipLaunchKernelGGL(scale_kernel, dim3(1), dim3(C), 0, stream,
                       wm, wa, ws, C, (float)Bc);

    dim3 grid(NSEG, (Bc * Cc) / WPB);   // 8 x 128 = 1024 blocks
    hipLaunchKernelGGL(mf_kernel, grid, dim3(THREADS), 0, stream,
                       x, kr, ki, ws, out, interleaved);
}